// Round 6
// baseline (57.705 us; speedup 1.0000x reference)
//
#include <hip/hip_runtime.h>
#include <float.h>

typedef float float2v __attribute__((ext_vector_type(2)));
typedef float float4v __attribute__((ext_vector_type(4)));

// Problem constants (fixed by the reference setup_inputs()).
#define N_BATCH 4
#define P1 8192
#define P2 8192
#define D 3

#define CHUNK 128                  // targets staged in LDS per block
#define NCHUNK (P2 / CHUNK)        // 64
#define NGRP (CHUNK / 8)           // 16 groups of 8 targets
#define RSRC 16                    // source points per thread
#define TPB 256
#define SRC_PER_BLK (TPB * RSRC)   // 4096
#define NSRCBLK (P1 / SRC_PER_BLK) // 2
#define NMIN (N_BATCH * P1)        // 32768 per-source mins
#define NBLOCKS (N_BATCH * NSRCBLK * NCHUNK)  // 512

#define FILLPAT 0x7F7F7F7Fu        // memset 0x7F: mins ~ 3.39e38, cnt start
#define LAST_TICKET (FILLPAT + (unsigned)NBLOCKS - 1u)

struct Grp { float4v x[2], y[2], z[2], w[2]; };

// Fully fused: compute + atomicMin merge + last-block final reduction.
__global__ __launch_bounds__(TPB, 2) void chamfer_fused(
        const float* __restrict__ src,
        const float* __restrict__ tgt,
        unsigned* __restrict__ mins,   // NMIN entries, pre-filled 0x7F7F7F7F
        unsigned* __restrict__ cnt,    // 1 entry, pre-filled 0x7F7F7F7F
        float* __restrict__ out) {
    const int bid = blockIdx.x;
    const int c   = bid % NCHUNK;
    const int sb  = (bid / NCHUNK) % NSRCBLK;
    const int n   = bid / (NCHUNK * NSRCBLK);
    const int t   = threadIdx.x;

    // SoA target tile: components scaled by -2, plus |y|^2.
    __shared__ __align__(16) float sX[CHUNK];
    __shared__ __align__(16) float sY[CHUNK];
    __shared__ __align__(16) float sZ[CHUNK];
    __shared__ __align__(16) float sW[CHUNK];
    __shared__ unsigned sLast;
    __shared__ float sred[TPB / 64];

    if (t < CHUNK) {
        const int j = c * CHUNK + t;
        const float* p = tgt + ((size_t)n * P2 + j) * D;
        const float y0 = p[0], y1 = p[1], y2 = p[2];
        sX[t] = -2.0f * y0;
        sY[t] = -2.0f * y1;
        sZ[t] = -2.0f * y2;
        sW[t] = y0 * y0 + y1 * y1 + y2 * y2;
    }
    __syncthreads();

    // Per-thread sources: packed broadcast registers {x,x} for v_pk_fma_f32.
    float2v bx0[RSRC], bx1[RSRC], bx2[RSRC];
    float m[RSRC];
#pragma unroll
    for (int i = 0; i < RSRC; ++i) {
        const int s = sb * SRC_PER_BLK + i * TPB + t;
        const float* p = src + ((size_t)n * P1 + s) * D;
        bx0[i] = (float2v){p[0], p[0]};
        bx1[i] = (float2v){p[1], p[1]};
        bx2[i] = (float2v){p[2], p[2]};
        m[i] = FLT_MAX;
    }

    // Software-pipelined groups of 8 targets: load group g+1's 8 quads from
    // LDS while computing group g (16 sources x 4 pk-halves x
    // (3 v_pk_fma_f32 + 1 v_min3_f32) = 256 VALU per group vs 8 ds_read_b128).
    Grp cur;
    {
        cur.x[0] = *(const float4v*)&sX[0]; cur.x[1] = *(const float4v*)&sX[4];
        cur.y[0] = *(const float4v*)&sY[0]; cur.y[1] = *(const float4v*)&sY[4];
        cur.z[0] = *(const float4v*)&sZ[0]; cur.z[1] = *(const float4v*)&sZ[4];
        cur.w[0] = *(const float4v*)&sW[0]; cur.w[1] = *(const float4v*)&sW[4];
    }
#pragma unroll
    for (int g = 0; g < NGRP; ++g) {
        Grp nxt;
        if (g + 1 < NGRP) {
            const int jb = (g + 1) * 8;
            nxt.x[0] = *(const float4v*)&sX[jb]; nxt.x[1] = *(const float4v*)&sX[jb + 4];
            nxt.y[0] = *(const float4v*)&sY[jb]; nxt.y[1] = *(const float4v*)&sY[jb + 4];
            nxt.z[0] = *(const float4v*)&sZ[jb]; nxt.z[1] = *(const float4v*)&sZ[jb + 4];
            nxt.w[0] = *(const float4v*)&sW[jb]; nxt.w[1] = *(const float4v*)&sW[jb + 4];
        }
#pragma unroll
        for (int i = 0; i < RSRC; ++i) {
#pragma unroll
            for (int h = 0; h < 2; ++h) {
                float2v d;
                d = __builtin_elementwise_fma(bx0[i], cur.x[h].xy, cur.w[h].xy);
                d = __builtin_elementwise_fma(bx1[i], cur.y[h].xy, d);
                d = __builtin_elementwise_fma(bx2[i], cur.z[h].xy, d);
                m[i] = fminf(fminf(m[i], d.x), d.y);
                d = __builtin_elementwise_fma(bx0[i], cur.x[h].zw, cur.w[h].zw);
                d = __builtin_elementwise_fma(bx1[i], cur.y[h].zw, d);
                d = __builtin_elementwise_fma(bx2[i], cur.z[h].zw, d);
                m[i] = fminf(fminf(m[i], d.x), d.y);
            }
        }
        if (g + 1 < NGRP) cur = nxt;
    }

    // Finalize per source: add x^2, clamp (commutes with min), merge via
    // bit-pattern atomicMin (valid total order for non-negative floats).
#pragma unroll
    for (int i = 0; i < RSRC; ++i) {
        const float xs = bx0[i].x * bx0[i].x + bx1[i].x * bx1[i].x
                       + bx2[i].x * bx2[i].x;
        const float v = fmaxf(xs + m[i], 0.0f);
        const int s = n * P1 + sb * SRC_PER_BLK + i * TPB + t;
        atomicMin(&mins[s], __float_as_uint(v));
    }

    // Last block to finish performs the final 128 KB sum.
    __threadfence();                               // release ws/mins writes
    if (t == 0) sLast = (atomicAdd(cnt, 1u) == LAST_TICKET) ? 1u : 0u;
    __syncthreads();
    if (sLast) {
        __threadfence();                           // acquire others' mins
        const float4v* mv = (const float4v*)mins;
        float ssum = 0.0f;
#pragma unroll
        for (int k = 0; k < NMIN / 4 / TPB; ++k) { // 32 coalesced b128 loads
            const float4v v = mv[(size_t)k * TPB + t];
            ssum += v.x + v.y + v.z + v.w;
        }
#pragma unroll
        for (int off = 32; off > 0; off >>= 1)
            ssum += __shfl_down(ssum, off, 64);
        const int lane = t & 63, w = t >> 6;
        if (lane == 0) sred[w] = ssum;
        __syncthreads();
        if (t == 0) {
            float s = 0.0f;
#pragma unroll
            for (int i = 0; i < TPB / 64; ++i) s += sred[i];
            out[0] = s * (1.0f / N_BATCH);         // batch_reduction='mean'
        }
    }
}

extern "C" void kernel_launch(void* const* d_in, const int* in_sizes, int n_in,
                              void* d_out, int out_size, void* d_ws, size_t ws_size,
                              hipStream_t stream) {
    const float* src = (const float*)d_in[0];  // (4, 8192, 3) f32
    const float* tgt = (const float*)d_in[1];  // (4, 8192, 3) f32
    float* out = (float*)d_out;                // scalar f32
    unsigned* mins = (unsigned*)d_ws;          // NMIN entries
    unsigned* cnt  = mins + NMIN;              // 1 entry

    // One tiny fill re-arms mins (+inf-ish) AND the ticket counter each call.
    hipMemsetAsync(d_ws, 0x7F, (size_t)NMIN * 4 + 4, stream);

    chamfer_fused<<<NBLOCKS, TPB, 0, stream>>>(src, tgt, mins, cnt, out);
}

// Round 7
// 48.089 us; speedup vs baseline: 1.2000x; 1.2000x over previous
//
#include <hip/hip_runtime.h>
#include <float.h>

typedef float float2v __attribute__((ext_vector_type(2)));
typedef float float4v __attribute__((ext_vector_type(4)));

// Problem constants (fixed by the reference setup_inputs()).
#define N_BATCH 4
#define P1 8192
#define P2 8192
#define D 3

#define TPB 256
#define RSRC 4                      // source points per thread
#define CHUNK 128                   // targets per block
#define NCHUNK (P2 / CHUNK)         // 64
#define NPAIRG (CHUNK / 2)          // 64 pair-groups per chunk
#define NMIN (N_BATCH * P1)         // 32768 sources total
#define SRC_PER_BLK (TPB * RSRC)    // 1024
#define NSB (NMIN / SRC_PER_BLK)    // 32 source blocks (global)
#define NPK (N_BATCH * P2 / 2)      // 16384 packed target pair-groups

struct Pk8 { float v[8]; };          // (-2xa,-2xb,-2ya,-2yb,-2za,-2zb,wa,wb)

// Prepass: pack target pairs pk-ready; also zero the output accumulator.
__global__ __launch_bounds__(TPB) void chamfer_prepack(
        const float* __restrict__ tgt, float* __restrict__ pk,
        float* __restrict__ out) {
    const int u = blockIdx.x * TPB + threadIdx.x;   // pair-group id
    if (u == 0) out[0] = 0.0f;
    if (u >= NPK) return;
    const int n = u >> 12;                          // batch (4096 pairs/batch)
    const int q = u & 4095;
    const float* pa = tgt + ((size_t)n * P2 + 2 * q) * D;
    const float xa = pa[0], ya = pa[1], za = pa[2];
    const float xb = pa[3], yb = pa[4], zb = pa[5];
    float4v* o = (float4v*)(pk + (size_t)u * 8);
    o[0] = (float4v){-2.0f * xa, -2.0f * xb, -2.0f * ya, -2.0f * yb};
    o[1] = (float4v){-2.0f * za, -2.0f * zb,
                     xa * xa + ya * ya + za * za,
                     xb * xb + yb * yb + zb * zb};
}

// Main: block (sb, c) computes, for its 1024 sources and 128-target chunk,
// min over targets of (y^2 - 2*x.y). Targets arrive via wave-uniform scalar
// loads (SMEM pipe) — no LDS, no syncthreads. Race-free store to ws[c][s].
__global__ __launch_bounds__(TPB, 6) void chamfer_main(
        const float* __restrict__ src,
        const Pk8* __restrict__ pk,
        float* __restrict__ ws) {
    const int bid = blockIdx.x;
    const int c   = bid & (NCHUNK - 1);      // target chunk
    const int sb  = bid >> 6;                // global source block (0..31)
    const int t   = threadIdx.x;
    const int n   = sb >> 3;                 // batch (8 source blocks/batch)
    const int pkbase = n * 4096 + c * NPAIRG;  // wave-uniform

    // Per-thread sources: packed broadcast {x,x} for v_pk_fma_f32.
    float2v bx0[RSRC], bx1[RSRC], bx2[RSRC];
    float m[RSRC];
#pragma unroll
    for (int i = 0; i < RSRC; ++i) {
        const int s = sb * SRC_PER_BLK + i * TPB + t;
        const float* p = src + (size_t)s * D;
        bx0[i] = (float2v){p[0], p[0]};
        bx1[i] = (float2v){p[1], p[1]};
        bx2[i] = (float2v){p[2], p[2]};
        m[i] = FLT_MAX;
    }

    // 64 pair-groups: each is one wave-uniform 32B scalar load feeding
    // RSRC x (3 v_pk_fma_f32 + 1 v_min3_f32).
#pragma unroll 4
    for (int q = 0; q < NPAIRG; ++q) {
        const Pk8 P = pk[pkbase + q];        // -> s_load_dwordx8 (uniform)
        const float2v X = {P.v[0], P.v[1]};
        const float2v Y = {P.v[2], P.v[3]};
        const float2v Z = {P.v[4], P.v[5]};
        const float2v W = {P.v[6], P.v[7]};
#pragma unroll
        for (int i = 0; i < RSRC; ++i) {
            float2v d;
            d = __builtin_elementwise_fma(bx0[i], X, W);
            d = __builtin_elementwise_fma(bx1[i], Y, d);
            d = __builtin_elementwise_fma(bx2[i], Z, d);
            m[i] = fminf(fminf(m[i], d.x), d.y);   // -> v_min3_f32
        }
    }

    // Race-free partial-min store (coalesced in t).
#pragma unroll
    for (int i = 0; i < RSRC; ++i) {
        const int s = sb * SRC_PER_BLK + i * TPB + t;
        ws[(size_t)c * NMIN + s] = m[i];
    }
}

// Reduce: per source, min over 64 chunk-partials, add x^2, clamp, sum.
__global__ __launch_bounds__(TPB) void chamfer_reduce(
        const float* __restrict__ ws,
        const float* __restrict__ src,
        float* __restrict__ out) {
    const int gid = blockIdx.x * TPB + threadIdx.x;  // source id

    float m = ws[gid];
#pragma unroll 8
    for (int c = 1; c < NCHUNK; ++c)
        m = fminf(m, ws[(size_t)c * NMIN + gid]);

    const float* p = src + (size_t)gid * D;
    const float xs = p[0] * p[0] + p[1] * p[1] + p[2] * p[2];
    float r = fmaxf(m + xs, 0.0f);

#pragma unroll
    for (int off = 32; off > 0; off >>= 1)
        r += __shfl_down(r, off, 64);
    __shared__ float sred[TPB / 64];
    const int lane = threadIdx.x & 63;
    const int w    = threadIdx.x >> 6;
    if (lane == 0) sred[w] = r;
    __syncthreads();
    if (threadIdx.x == 0) {
        float s = 0.0f;
#pragma unroll
        for (int i = 0; i < TPB / 64; ++i) s += sred[i];
        atomicAdd(out, s * (1.0f / N_BATCH));  // batch_reduction='mean'
    }
}

extern "C" void kernel_launch(void* const* d_in, const int* in_sizes, int n_in,
                              void* d_out, int out_size, void* d_ws, size_t ws_size,
                              hipStream_t stream) {
    const float* src = (const float*)d_in[0];  // (4, 8192, 3) f32
    const float* tgt = (const float*)d_in[1];  // (4, 8192, 3) f32
    float* out = (float*)d_out;                // scalar f32
    float* pk  = (float*)d_ws;                 // 16384 * 32B = 512 KB
    float* ws  = pk + (size_t)NPK * 8;         // 64 * 32768 * 4B = 8 MB

    chamfer_prepack<<<(NPK + TPB - 1) / TPB, TPB, 0, stream>>>(tgt, pk, out);

    chamfer_main<<<NSB * NCHUNK, TPB, 0, stream>>>(src, (const Pk8*)pk, ws);

    chamfer_reduce<<<NMIN / TPB, TPB, 0, stream>>>(ws, src, out);
}

// Round 8
// 35.730 us; speedup vs baseline: 1.6151x; 1.3459x over previous
//
#include <hip/hip_runtime.h>
#include <float.h>

typedef float float2v __attribute__((ext_vector_type(2)));
typedef float float4v __attribute__((ext_vector_type(4)));

// Problem constants (fixed by the reference setup_inputs()).
#define N_BATCH 4
#define P1 8192
#define P2 8192
#define D 3

#define CHUNK 128                  // targets staged in LDS per block
#define NCHUNK (P2 / CHUNK)        // 64
#define NSTEP (CHUNK / 4)          // 32 steps of 4 targets
#define RSRC 8                     // source points per thread
#define TPB 256
#define SRC_PER_BLK (TPB * RSRC)   // 2048
#define NSRCBLK (P1 / SRC_PER_BLK) // 4
#define NMIN (N_BATCH * P1)        // 32768 per-source mins

#define TPB_R 128                  // reduce kernel block size

// Main pass: block (n, sb, c) computes, for its 2048 sources and its
// 128-target chunk, min over targets of (y^2 - 2*x.y) with v_pk_fma_f32.
// LDS is SoA ([comp][128]) so one ds_read_b128 covers 4 targets' worth of
// one component. KEY CHANGE vs R5: each wave walks the 32 steps starting at
// a distinct rotation offset (min is order-independent) so co-resident
// waves' LDS-read bursts and VALU bursts interleave instead of convoying.
__global__ __launch_bounds__(TPB, 4) void chamfer_main(
        const float* __restrict__ src,
        const float* __restrict__ tgt,
        float* __restrict__ ws,
        float* __restrict__ out) {
    const int bid = blockIdx.x;
    const int c   = bid % NCHUNK;
    const int sb  = (bid / NCHUNK) % NSRCBLK;
    const int n   = bid / (NCHUNK * NSRCBLK);
    const int t   = threadIdx.x;

    if (bid == 0 && t == 0) out[0] = 0.0f;

    // SoA target tile: sT[0..127]=-2x, [128..255]=-2y, [256..383]=-2z,
    // [384..511]=|y|^2.  Byte offsets 0 / 512 / 1024 / 1536.
    __shared__ __align__(16) float sT[4 * CHUNK];

    if (t < CHUNK) {
        const int j = c * CHUNK + t;
        const float* p = tgt + ((size_t)n * P2 + j) * D;
        const float y0 = p[0], y1 = p[1], y2 = p[2];
        sT[t]             = -2.0f * y0;
        sT[CHUNK + t]     = -2.0f * y1;
        sT[2 * CHUNK + t] = -2.0f * y2;
        sT[3 * CHUNK + t] = y0 * y0 + y1 * y1 + y2 * y2;
    }
    __syncthreads();

    // Per-thread sources: packed broadcast {x,x} for v_pk_fma_f32.
    float2v bx0[RSRC], bx1[RSRC], bx2[RSRC];
    float m[RSRC];
#pragma unroll
    for (int i = 0; i < RSRC; ++i) {
        const int s = sb * SRC_PER_BLK + i * TPB + t;
        const float* p = src + ((size_t)n * P1 + s) * D;
        bx0[i] = (float2v){p[0], p[0]};
        bx1[i] = (float2v){p[1], p[1]};
        bx2[i] = (float2v){p[2], p[2]};
        m[i] = FLT_MAX;
    }

    // Wave-phase stagger: wave w of co-resident block (bid>>8) starts at a
    // distinct step among 16 phases spread over the 32 steps.
    const int w = t >> 6;
    const int start = ((w << 3) | (((bid >> 8) & 3) << 1)) & (NSTEP - 1);

    // Each step: 4 ds_read_b128 (one 4-target quad per component), then
    // 8 sources x 2 pk-pairs x (3 v_pk_fma_f32 + 1 v_min3_f32) = 64 VALU.
#pragma unroll 4
    for (int s = 0; s < NSTEP; ++s) {
        const int step = (s + start) & (NSTEP - 1);
        const int fb = step * 4;                   // float index of quad
        const float4v X = *(const float4v*)&sT[fb];
        const float4v Y = *(const float4v*)&sT[CHUNK + fb];
        const float4v Z = *(const float4v*)&sT[2 * CHUNK + fb];
        const float4v W = *(const float4v*)&sT[3 * CHUNK + fb];
#pragma unroll
        for (int i = 0; i < RSRC; ++i) {
            float2v d;
            d = __builtin_elementwise_fma(bx0[i], X.xy, W.xy);
            d = __builtin_elementwise_fma(bx1[i], Y.xy, d);
            d = __builtin_elementwise_fma(bx2[i], Z.xy, d);
            m[i] = fminf(fminf(m[i], d.x), d.y);   // -> v_min3_f32
            d = __builtin_elementwise_fma(bx0[i], X.zw, W.zw);
            d = __builtin_elementwise_fma(bx1[i], Y.zw, d);
            d = __builtin_elementwise_fma(bx2[i], Z.zw, d);
            m[i] = fminf(fminf(m[i], d.x), d.y);
        }
    }

    // Race-free partial-min store (coalesced per i).
#pragma unroll
    for (int i = 0; i < RSRC; ++i) {
        const int s = n * P1 + sb * SRC_PER_BLK + i * TPB + t;
        ws[(size_t)c * NMIN + s] = m[i];
    }
}

// Reduce: per source, min over 64 chunk-partials (tree for ILP), add x^2,
// clamp, block-sum, one atomicAdd per block.
__global__ __launch_bounds__(TPB_R) void chamfer_reduce(
        const float* __restrict__ ws,
        const float* __restrict__ src,
        float* __restrict__ out) {
    const int gid = blockIdx.x * TPB_R + threadIdx.x;  // source id

    float v[NCHUNK];
#pragma unroll
    for (int c = 0; c < NCHUNK; ++c)
        v[c] = ws[(size_t)c * NMIN + gid];
#pragma unroll
    for (int s = NCHUNK / 2; s > 0; s >>= 1)
#pragma unroll
        for (int c = 0; c < s; ++c)
            v[c] = fminf(v[c], v[c + s]);

    const float* p = src + (size_t)gid * D;
    const float xs = p[0] * p[0] + p[1] * p[1] + p[2] * p[2];
    float r = fmaxf(v[0] + xs, 0.0f);

#pragma unroll
    for (int off = 32; off > 0; off >>= 1)
        r += __shfl_down(r, off, 64);
    __shared__ float sred[TPB_R / 64];
    const int lane = threadIdx.x & 63;
    const int w    = threadIdx.x >> 6;
    if (lane == 0) sred[w] = r;
    __syncthreads();
    if (threadIdx.x == 0) {
        float s = 0.0f;
#pragma unroll
        for (int i = 0; i < TPB_R / 64; ++i) s += sred[i];
        atomicAdd(out, s * (1.0f / N_BATCH));  // batch_reduction='mean'
    }
}

extern "C" void kernel_launch(void* const* d_in, const int* in_sizes, int n_in,
                              void* d_out, int out_size, void* d_ws, size_t ws_size,
                              hipStream_t stream) {
    const float* src = (const float*)d_in[0];  // (4, 8192, 3) f32
    const float* tgt = (const float*)d_in[1];  // (4, 8192, 3) f32
    float* out = (float*)d_out;                // scalar f32
    float* ws  = (float*)d_ws;                 // 64 * 32768 * 4B = 8 MB

    const int nblocks = N_BATCH * NSRCBLK * NCHUNK;  // 4*4*64 = 1024
    chamfer_main<<<nblocks, TPB, 0, stream>>>(src, tgt, ws, out);

    chamfer_reduce<<<NMIN / TPB_R, TPB_R, 0, stream>>>(ws, src, out);
}